// Round 6
// baseline (36.969 us; speedup 1.0000x reference)
//
#include <hip/hip_runtime.h>

#define AGENT_THRESH 0.5f
#define X_DIS_THRESH 1.5f
#define Y_DIS_THRESH 3.0f
#define DIS2_THRESH  9.0f
#define LOSS_WEIGHT  1.0f
#define FLT_BIG      3.402823466e+38f

constexpr int B = 128, A = 2048, M = 6, T = 12, C = 10;
constexpr int APB = 256;            // threads = agents per block
constexpr int CHUNKS = A / APB;     // 8
constexpr int NBLK = B * CHUNKS;    // 1024
constexpr int SLOTS = T * 2;        // 24
constexpr int GRP = 10;             // reducer threads per slot

// smem union (floats):
//   staging: scores [0,2560) | cls [2560,4096) | ap [4096,4608)
//   reduce:  sred 256x25 [0,6400) | spart [6400,6640) | wpart [6640,6644)
constexpr int SMEM_F = 6656;        // 26.6 KB

__global__ __launch_bounds__(APB) void pcl_fused_kernel(
    const float* __restrict__ ego,          // [B,T,2]
    const float* __restrict__ agent_preds,  // [B,A,2]
    const float* __restrict__ afp,          // [B,A,M,T,2]
    const float* __restrict__ scores,       // [B,A,C]
    const float* __restrict__ cls,          // [B,A,M]
    unsigned int* __restrict__ blockmins_u, // [NBLK*24] float bits
    unsigned int* __restrict__ counter,     // modulo ticket (never reset)
    float* __restrict__ out)
{
    const int bid   = blockIdx.x;
    const int b     = bid / CHUNKS;
    const int chunk = bid % CHUNKS;
    const int tid   = threadIdx.x;
    const size_t base = (size_t)b * A + chunk * APB;   // first agent of block

    __shared__ float smem[SMEM_F];
    __shared__ float egoraw[SLOTS], predx[T], predy[T];
    __shared__ int slast;

    // ---- coalesced float4 staging of dense per-block slices --------------
    {
        const float4* g = (const float4*)(scores + base * C);     // 640 vec4
        float4* l = (float4*)&smem[0];
        for (int i = tid; i < (APB * C) / 4; i += APB) l[i] = g[i];
    }
    {
        const float4* g = (const float4*)(cls + base * M);        // 384 vec4
        float4* l = (float4*)&smem[2560];
        for (int i = tid; i < (APB * M) / 4; i += APB) l[i] = g[i];
    }
    {
        const float4* g = (const float4*)(agent_preds + base * 2); // 128 vec4
        float4* l = (float4*)&smem[4096];
        for (int i = tid; i < (APB * 2) / 4; i += APB) l[i] = g[i];
    }
    if (tid < SLOTS) egoraw[tid] = ego[(size_t)b * SLOTS + tid];
    __syncthreads();

    if (tid < SLOTS) {                       // wave-parallel ego prefix
        const int coord = (tid >= T) ? 1 : 0;
        const int tt    = tid - T * coord;
        float s = 0.f;
        for (int i = 0; i <= tt; ++i) s += egoraw[2 * i + coord];
        if (coord) predy[tt] = s; else predx[tt] = s;
    }

    // ---- per-agent values from LDS (2-way bank aliasing: free) -----------
    float sv[C], cv[M];
    #pragma unroll
    for (int c = 0; c < C; ++c) sv[c] = smem[tid * C + c];
    #pragma unroll
    for (int m = 0; m < M; ++m) cv[m] = smem[2560 + tid * M + m];
    const float apx = smem[4096 + tid * 2 + 0];
    const float apy = smem[4096 + tid * 2 + 1];
    __syncthreads();                         // staging reads done; pred ready

    // ---- validity / best mode / gather / per-thread mins ------------------
    float ms = sv[0];
    int   mi = 0;
    #pragma unroll
    for (int c = 1; c < C; ++c)
        if (sv[c] > ms) { ms = sv[c]; mi = c; }
    const bool valid = (ms >= AGENT_THRESH) && (mi <= 4);

    float p[SLOTS];
    #pragma unroll
    for (int k = 0; k < SLOTS; ++k) p[k] = FLT_BIG;

    if (valid) {
        float mc = cv[0];
        int   mm = 0;
        #pragma unroll
        for (int m = 1; m < M; ++m)
            if (cv[m] > mc) { mc = cv[m]; mm = m; }

        const size_t ba = base + tid;
        const float4* fp = (const float4*)(afp + (ba * M + mm) * (size_t)SLOTS);
        float4 f0 = fp[0], f1 = fp[1], f2 = fp[2], f3 = fp[3], f4 = fp[4], f5 = fp[5];
        float dxv[SLOTS];
        dxv[0]=f0.x; dxv[1]=f0.y; dxv[2]=f0.z; dxv[3]=f0.w;
        dxv[4]=f1.x; dxv[5]=f1.y; dxv[6]=f1.z; dxv[7]=f1.w;
        dxv[8]=f2.x; dxv[9]=f2.y; dxv[10]=f2.z; dxv[11]=f2.w;
        dxv[12]=f3.x; dxv[13]=f3.y; dxv[14]=f3.z; dxv[15]=f3.w;
        dxv[16]=f4.x; dxv[17]=f4.y; dxv[18]=f4.z; dxv[19]=f4.w;
        dxv[20]=f5.x; dxv[21]=f5.y; dxv[22]=f5.z; dxv[23]=f5.w;

        float csx = 0.f, csy = 0.f;
        #pragma unroll
        for (int t = 0; t < T; ++t) {
            csx += dxv[2 * t + 0];
            csy += dxv[2 * t + 1];
            const float dx = predx[t] - (apx + csx);
            const float dy = predy[t] - (apy + csy);
            const bool hit = (dx * dx + dy * dy <= DIS2_THRESH);
            p[2 * t + 0] = fminf(p[2 * t + 0], hit ? fabsf(dx) : FLT_BIG);
            p[2 * t + 1] = fminf(p[2 * t + 1], hit ? fabsf(dy) : FLT_BIG);
        }
    }

    // ---- transpose-reduce in LDS (reuse staging space) --------------------
    #pragma unroll
    for (int k = 0; k < SLOTS; ++k) smem[tid * 25 + k] = p[k];
    __syncthreads();

    if (tid < SLOTS * GRP) {
        const int s = tid % SLOTS;
        const int g = tid / SLOTS;
        float pm = FLT_BIG;
        for (int r = g; r < APB; r += GRP) pm = fminf(pm, smem[r * 25 + s]);
        smem[6400 + tid] = pm;
    }
    __syncthreads();

    if (tid < SLOTS) {
        float m = smem[6400 + tid];
        #pragma unroll
        for (int g = 1; g < GRP; ++g) m = fminf(m, smem[6400 + g * SLOTS + tid]);
        // device-scope atomic store: no init/idempotence dependence
        atomicExch(&blockmins_u[(size_t)bid * SLOTS + tid], __float_as_uint(m));
    }
    __syncthreads();

    // ---- last-block-done final reduce (modulo ticket: poison-immune) ------
    if (tid == 0) {
        __threadfence();
        unsigned int prev = atomicAdd(counter, 1u);
        slast = ((prev % (unsigned)NBLK) == (unsigned)(NBLK - 1)) ? 1 : 0;
    }
    __syncthreads();

    if (slast) {
        __threadfence();
        float s = 0.f;
        for (int pi = tid; pi < B * SLOTS; pi += APB) {   // 12 pairs/thread
            const int bb = pi / SLOTS;
            const int sl = pi % SLOTS;
            unsigned int mu =
                atomicAdd(&blockmins_u[((size_t)bb * CHUNKS + 0) * SLOTS + sl], 0u);
            #pragma unroll
            for (int c2 = 1; c2 < CHUNKS; ++c2) {
                unsigned int v =
                    atomicAdd(&blockmins_u[((size_t)bb * CHUNKS + c2) * SLOTS + sl], 0u);
                mu = (v < mu) ? v : mu;    // non-negative floats: uint order ok
            }
            const float mv  = __uint_as_float(mu);
            const float thr = (sl & 1) ? Y_DIS_THRESH : X_DIS_THRESH;
            s += (mv > thr) ? 0.f : (thr - mv);
        }
        #pragma unroll
        for (int off = 32; off > 0; off >>= 1) s += __shfl_down(s, off, 64);
        if ((tid & 63) == 0) smem[6640 + (tid >> 6)] = s;
        __syncthreads();                   // uniform branch: block-wide legal
        if (tid == 0) {
            float tot = smem[6640] + smem[6641] + smem[6642] + smem[6643];
            out[0] = LOSS_WEIGHT * tot / (float)(B * SLOTS);
        }
    }
}

extern "C" void kernel_launch(void* const* d_in, const int* in_sizes, int n_in,
                              void* d_out, int out_size, void* d_ws, size_t ws_size,
                              hipStream_t stream) {
    const float* ego         = (const float*)d_in[0];  // [B,T,2]
    const float* agent_preds = (const float*)d_in[1];  // [B,A,2]
    const float* afp         = (const float*)d_in[2];  // [B,A,M,T,2]
    const float* scores      = (const float*)d_in[3];  // [B,A,C]
    const float* cls         = (const float*)d_in[4];  // [B,A,M]
    float* out               = (float*)d_out;

    unsigned int* blockmins_u = (unsigned int*)d_ws;               // 96 KB
    unsigned int* counter     = (unsigned int*)d_ws + NBLK * SLOTS + 32;

    pcl_fused_kernel<<<NBLK, APB, 0, stream>>>(
        ego, agent_preds, afp, scores, cls, blockmins_u, counter, out);
}

// Round 7
// 20.746 us; speedup vs baseline: 1.7820x; 1.7820x over previous
//
#include <hip/hip_runtime.h>

#define AGENT_THRESH 0.5f
#define X_DIS_THRESH 1.5f
#define Y_DIS_THRESH 3.0f
#define DIS2_THRESH  9.0f
#define LOSS_WEIGHT  1.0f
#define FLT_BIG      3.402823466e+38f

constexpr int B = 128, A = 2048, M = 6, T = 12, C = 10;
constexpr int APB = 256;            // threads = agents per block
constexpr int CHUNKS = A / APB;     // 8
constexpr int NBLK = B * CHUNKS;    // 1024
constexpr int SLOTS = T * 2;        // 24
constexpr int GRP = 10;             // reducer threads per slot

// smem union (floats):
//   phase1 staging: scores [0,2560) | cls [2560,4096) | ap [4096,4608)
//   phase2 reduce:  sred 256x25 [0,6400) | spart [6400,6640)
constexpr int SMEM_F = 6656;        // 26.6 KB

// Kernel 1: identical math to the 20.1us R3 kernel; ONLY change is that
// scores/cls/agent_preds are staged into LDS with dense float4 loads
// (A/B test of the transaction-amplification theory).
__global__ __launch_bounds__(APB) void pcl_main_kernel(
    const float* __restrict__ ego,          // [B,T,2]
    const float* __restrict__ agent_preds,  // [B,A,2]
    const float* __restrict__ afp,          // [B,A,M,T,2]
    const float* __restrict__ scores,       // [B,A,C]
    const float* __restrict__ cls,          // [B,A,M]
    float* __restrict__ blockmins)          // [NBLK, 24]
{
    const int bid   = blockIdx.x;
    const int b     = bid / CHUNKS;
    const int chunk = bid % CHUNKS;
    const int tid   = threadIdx.x;
    const size_t base = (size_t)b * A + chunk * APB;   // first agent of block

    __shared__ float smem[SMEM_F];
    __shared__ float egoraw[SLOTS], predx[T], predy[T];

    // ---- coalesced float4 staging of dense per-block slices --------------
    {
        const float4* g = (const float4*)(scores + base * C);     // 640 vec4
        float4* l = (float4*)&smem[0];
        #pragma unroll
        for (int i = 0; i < 3; ++i) {
            int idx = tid + i * APB;
            if (idx < (APB * C) / 4) l[idx] = g[idx];
        }
    }
    {
        const float4* g = (const float4*)(cls + base * M);        // 384 vec4
        float4* l = (float4*)&smem[2560];
        #pragma unroll
        for (int i = 0; i < 2; ++i) {
            int idx = tid + i * APB;
            if (idx < (APB * M) / 4) l[idx] = g[idx];
        }
    }
    {
        const float4* g = (const float4*)(agent_preds + base * 2); // 128 vec4
        float4* l = (float4*)&smem[4096];
        if (tid < (APB * 2) / 4) l[tid] = g[tid];
    }
    if (tid < SLOTS) egoraw[tid] = ego[(size_t)b * SLOTS + tid];
    __syncthreads();

    if (tid < SLOTS) {                       // wave-parallel ego prefix
        const int coord = (tid >= T) ? 1 : 0;
        const int tt    = tid - T * coord;
        float s = 0.f;
        for (int i = 0; i <= tt; ++i) s += egoraw[2 * i + coord];
        if (coord) predy[tt] = s; else predx[tt] = s;
    }

    // ---- per-agent values from LDS ----------------------------------------
    float sv[C], cv[M];
    #pragma unroll
    for (int c = 0; c < C; ++c) sv[c] = smem[tid * C + c];
    #pragma unroll
    for (int m = 0; m < M; ++m) cv[m] = smem[2560 + tid * M + m];
    const float apx = smem[4096 + tid * 2 + 0];
    const float apy = smem[4096 + tid * 2 + 1];
    __syncthreads();                         // staging reads done; pred ready

    // ---- validity / best mode / gather / per-thread mins ------------------
    float ms = sv[0];
    int   mi = 0;
    #pragma unroll
    for (int c = 1; c < C; ++c)
        if (sv[c] > ms) { ms = sv[c]; mi = c; }
    const bool valid = (ms >= AGENT_THRESH) && (mi <= 4);

    float p[SLOTS];
    #pragma unroll
    for (int k = 0; k < SLOTS; ++k) p[k] = FLT_BIG;

    if (valid) {
        float mc = cv[0];
        int   mm = 0;
        #pragma unroll
        for (int m = 1; m < M; ++m)
            if (cv[m] > mc) { mc = cv[m]; mm = m; }

        const size_t ba = base + tid;
        const float4* fp = (const float4*)(afp + (ba * M + mm) * (size_t)SLOTS);
        float4 f0 = fp[0], f1 = fp[1], f2 = fp[2], f3 = fp[3], f4 = fp[4], f5 = fp[5];
        float dxv[SLOTS];
        dxv[0]=f0.x; dxv[1]=f0.y; dxv[2]=f0.z; dxv[3]=f0.w;
        dxv[4]=f1.x; dxv[5]=f1.y; dxv[6]=f1.z; dxv[7]=f1.w;
        dxv[8]=f2.x; dxv[9]=f2.y; dxv[10]=f2.z; dxv[11]=f2.w;
        dxv[12]=f3.x; dxv[13]=f3.y; dxv[14]=f3.z; dxv[15]=f3.w;
        dxv[16]=f4.x; dxv[17]=f4.y; dxv[18]=f4.z; dxv[19]=f4.w;
        dxv[20]=f5.x; dxv[21]=f5.y; dxv[22]=f5.z; dxv[23]=f5.w;

        float csx = 0.f, csy = 0.f;
        #pragma unroll
        for (int t = 0; t < T; ++t) {
            csx += dxv[2 * t + 0];
            csy += dxv[2 * t + 1];
            const float dx = predx[t] - (apx + csx);
            const float dy = predy[t] - (apy + csy);
            const bool hit = (dx * dx + dy * dy <= DIS2_THRESH);
            p[2 * t + 0] = fminf(p[2 * t + 0], hit ? fabsf(dx) : FLT_BIG);
            p[2 * t + 1] = fminf(p[2 * t + 1], hit ? fabsf(dy) : FLT_BIG);
        }
    }

    // ---- transpose-reduce in LDS (reuse staging space) --------------------
    #pragma unroll
    for (int k = 0; k < SLOTS; ++k) smem[tid * 25 + k] = p[k];
    __syncthreads();

    if (tid < SLOTS * GRP) {
        const int s = tid % SLOTS;
        const int g = tid / SLOTS;
        float pm = FLT_BIG;
        for (int r = g; r < APB; r += GRP) pm = fminf(pm, smem[r * 25 + s]);
        smem[6400 + tid] = pm;
    }
    __syncthreads();

    if (tid < SLOTS) {
        float m = smem[6400 + tid];
        #pragma unroll
        for (int g = 1; g < GRP; ++g) m = fminf(m, smem[6400 + g * SLOTS + tid]);
        blockmins[(size_t)bid * SLOTS + tid] = m;
    }
}

// Kernel 2: single block reduces 1024x24 table, hinge, mean (R3 version).
__global__ __launch_bounds__(256) void pcl_finalize_kernel(
    const float* __restrict__ blockmins, float* __restrict__ out)
{
    float s = 0.f;
    for (int slot = threadIdx.x; slot < B * SLOTS; slot += 256) {
        const int b  = slot / SLOTS;
        const int sc = slot % SLOTS;
        float m = blockmins[((size_t)b * CHUNKS + 0) * SLOTS + sc];
        #pragma unroll
        for (int j = 1; j < CHUNKS; ++j)
            m = fminf(m, blockmins[((size_t)b * CHUNKS + j) * SLOTS + sc]);
        const float thr = (sc & 1) ? Y_DIS_THRESH : X_DIS_THRESH;
        s += (m > thr) ? 0.f : (thr - m);
    }
    #pragma unroll
    for (int off = 32; off > 0; off >>= 1) s += __shfl_down(s, off, 64);
    __shared__ float wsum[4];
    const int wid = threadIdx.x >> 6;
    if ((threadIdx.x & 63) == 0) wsum[wid] = s;
    __syncthreads();
    if (threadIdx.x == 0) {
        float tot = wsum[0] + wsum[1] + wsum[2] + wsum[3];
        out[0] = LOSS_WEIGHT * tot / (float)(B * SLOTS);
    }
}

extern "C" void kernel_launch(void* const* d_in, const int* in_sizes, int n_in,
                              void* d_out, int out_size, void* d_ws, size_t ws_size,
                              hipStream_t stream) {
    const float* ego         = (const float*)d_in[0];  // [B,T,2]
    const float* agent_preds = (const float*)d_in[1];  // [B,A,2]
    const float* afp         = (const float*)d_in[2];  // [B,A,M,T,2]
    const float* scores      = (const float*)d_in[3];  // [B,A,C]
    const float* cls         = (const float*)d_in[4];  // [B,A,M]
    float* out               = (float*)d_out;
    float* blockmins         = (float*)d_ws;           // NBLK*24 floats = 96 KB

    pcl_main_kernel<<<NBLK, APB, 0, stream>>>(
        ego, agent_preds, afp, scores, cls, blockmins);
    pcl_finalize_kernel<<<1, 256, 0, stream>>>(blockmins, out);
}